// Round 13
// baseline (4921.879 us; speedup 1.0000x reference)
//
#include <hip/hip_runtime.h>
#include <math.h>

#define B_  32
#define T_  512
#define H_  1024
#define G4_ 4096
#define NT  512
#define ROWP 1032   // padded LDS row (f16): 2064 B
#define WROW 264    // load_wfrags bounce row pad
#define SENT 0xFFFFFFFFu

typedef __attribute__((ext_vector_type(8))) _Float16 f16x8;
typedef __attribute__((ext_vector_type(4))) float   f32x4;

__device__ __forceinline__ float hardsig(float z) {
    return fminf(fmaxf(0.2f * z + 0.5f, 0.0f), 1.0f);
}
__device__ __forceinline__ float fast_tanh(float x) {
    float ax = fabsf(x);
    float e  = __expf(-2.0f * ax);
    float t  = (1.0f - e) / (1.0f + e);
    return copysignf(t, x);
}
__device__ __forceinline__ unsigned ldA(const unsigned* p) {
    return __hip_atomic_load(p, __ATOMIC_RELAXED, __HIP_MEMORY_SCOPE_AGENT);
}
__device__ __forceinline__ void stA32(unsigned* p, unsigned v) {
    __hip_atomic_store(p, v, __ATOMIC_RELAXED, __HIP_MEMORY_SCOPE_AGENT);
}
__device__ __forceinline__ unsigned long long ldA64(const void* p) {
    return __hip_atomic_load((const unsigned long long*)p, __ATOMIC_RELAXED, __HIP_MEMORY_SCOPE_AGENT);
}
__device__ __forceinline__ void stA64(void* p, unsigned long long v) {
    __hip_atomic_store((unsigned long long*)p, v, __ATOMIC_RELAXED, __HIP_MEMORY_SCOPE_AGENT);
}
__device__ __forceinline__ float f16bits_to_f(unsigned short us) {
    _Float16 hf; __builtin_memcpy(&hf, &us, 2);
    return (float)hf;
}
__device__ __forceinline__ unsigned umin2(unsigned a, unsigned b) { return a < b ? a : b; }

// Poll-stage 64 KiB (src -> LDS dst): 512 threads x 8 granules x 16 B.
// Data IS the ready flag: granule halves (8B atomic stores) poll != SENT.
__device__ __forceinline__ void stage_poll(const char* src, char* dst, int tid) {
    unsigned long long a[8], b[8];
    #pragma unroll
    for (int it = 0; it < 8; ++it) {
        const char* p = src + tid * 16 + it * 8192;
        a[it] = ldA64(p); b[it] = ldA64(p + 8);
    }
    unsigned pend = 0xFFu;
    while (true) {
        unsigned np = 0;
        #pragma unroll
        for (int it = 0; it < 8; ++it)
            if (pend & (1u << it))
                if ((unsigned)a[it] == SENT || (unsigned)b[it] == SENT) np |= (1u << it);
        #pragma unroll
        for (int it = 0; it < 8; ++it)
            if ((pend & (1u << it)) && !(np & (1u << it))) {
                const int fb = tid * 16 + it * 8192;
                unsigned long long* d = (unsigned long long*)(dst + (fb >> 11) * 2064 + (fb & 2047));
                d[0] = a[it]; d[1] = b[it];
            }
        pend = np;
        if (!pend) break;
        #pragma unroll
        for (int it = 0; it < 8; ++it)
            if (pend & (1u << it)) {
                const char* p = src + tid * 16 + it * 8192;
                a[it] = ldA64(p); b[it] = ldA64(p + 8);
            }
    }
}

// Stage a [1024 k] x [64 gate-col] fp32 weight slice into per-wave MFMA B-fragments.
__device__ __forceinline__ void load_wfrags(const float* M, int colbase, int myrow,
                                            int koff, bool keep, f16x8* wf, _Float16* st) {
    for (int kc = 0; kc < 4; ++kc) {
        __syncthreads();
        #pragma unroll
        for (int it = 0; it < 4; ++it) {
            int id  = it * NT + (int)threadIdx.x;
            int kl  = id >> 3, gc8 = id & 7;
            int gcol = (gc8 >> 1) * 1024 + colbase + (gc8 & 1) * 8;
            const float* src = M + (size_t)(kc * 256 + kl) * G4_ + gcol;
            float4 v0 = *(const float4*)src;
            float4 v1 = *(const float4*)(src + 4);
            int rb = gc8 * 8;
            st[(rb+0)*WROW+kl]=(_Float16)v0.x; st[(rb+1)*WROW+kl]=(_Float16)v0.y;
            st[(rb+2)*WROW+kl]=(_Float16)v0.z; st[(rb+3)*WROW+kl]=(_Float16)v0.w;
            st[(rb+4)*WROW+kl]=(_Float16)v1.x; st[(rb+5)*WROW+kl]=(_Float16)v1.y;
            st[(rb+6)*WROW+kl]=(_Float16)v1.z; st[(rb+7)*WROW+kl]=(_Float16)v1.w;
        }
        __syncthreads();
        if (keep) {
            #pragma unroll
            for (int kj = 0; kj < 8; ++kj)
                wf[kc*8+kj] = *(const f16x8*)&st[myrow * WROW + kj * 32 + koff];
        }
    }
    __syncthreads();
}

// flags: dom0 coarse @ ctr[db*2+w] (every 8 steps; ring guard), engine @ ctr[384+e].

__global__ __launch_bounds__(NT, 1)
void lstm13(const float* __restrict__ x,
            const float* __restrict__ W0, const float* __restrict__ U0, const float* __restrict__ b0,
            const float* __restrict__ W1, const float* __restrict__ U1, const float* __restrict__ b1,
            _Float16* __restrict__ h1,       // [T][B][H] fp16, 0xFF-sentinel
            _Float16* __restrict__ h2,       // [T][B][H] fp16, 0xFF-sentinel
            _Float16* __restrict__ xzr,      // [4][8][B][4H] fp16 ring (b0 folded)
            const _Float16* __restrict__ zp, // [B][H] fp16 zeros
            unsigned* __restrict__ ctr,
            float* __restrict__ out)         // [B][H] fp32
{
    __shared__ __align__(16) char smem[149504];

    const int tid = threadIdx.x, bid = blockIdx.x;
    const int w = tid >> 6, l = tid & 63;
    const int koff = (l >> 4) * 8;

    // ============================ xz ENGINE (bid 128..191) ============================
    if (bid >= 128) {
        _Float16* Wl = (_Float16*)smem;
        const int e = bid - 128, gbase = e * 64;
        for (int fi = tid; fi < 16384; fi += NT) {
            const int k = fi >> 4, rem = fi & 15;
            const float* src = W0 + (size_t)k * G4_ + gbase + rem * 4;
            float4 v = *(const float4*)src;
            const int kiG = k >> 5, jsub = 16 * ((k & 31) >> 3), e8 = k & 7;
            #pragma unroll
            for (int c = 0; c < 4; ++c) {
                const int j = rem * 4 + c, nf = j >> 4, lane = (j & 15) + jsub;
                float fv = (c == 0) ? v.x : (c == 1) ? v.y : (c == 2) ? v.z : v.w;
                Wl[((nf * 32 + kiG) * 64 + lane) * 8 + e8] = (_Float16)fv;
            }
        }
        float bb0[4];
        #pragma unroll
        for (int nf = 0; nf < 4; ++nf) bb0[nf] = b0[gbase + nf * 16 + (l & 15)];
        __syncthreads();

        for (int c = 0; c < 64; ++c) {
            if (c >= 4) {   // ring-slot reuse guard (dom0 coarse flags, multiples of 8)
                if (w == 0) {
                    const unsigned need = (unsigned)(8 * c - 24);
                    while (true) {
                        unsigned v = umin2(ldA(&ctr[2 * l]), ldA(&ctr[2 * l + 1]));
                        if (__all((int)(v >= need))) break;
                        __builtin_amdgcn_s_sleep(1);
                    }
                }
                __syncthreads();
            }
            f32x4 acc[2][4];
            #pragma unroll
            for (int p = 0; p < 2; ++p)
                #pragma unroll
                for (int nf = 0; nf < 4; ++nf) acc[p][nf] = (f32x4){0.f, 0.f, 0.f, 0.f};
            const float* xrow[2];
            #pragma unroll
            for (int p = 0; p < 2; ++p) {
                const int m = (w * 2 + p) * 16 + (l & 15);
                xrow[p] = x + ((size_t)(m & 31) * T_ + (8 * c + (m >> 5))) * 1024;
            }
            #pragma unroll 4
            for (int kiG = 0; kiG < 32; ++kiG) {
                const int kk = kiG * 32 + koff;
                f16x8 af[2];
                #pragma unroll
                for (int p = 0; p < 2; ++p) {
                    float4 v0 = *(const float4*)&xrow[p][kk];
                    float4 v1 = *(const float4*)&xrow[p][kk + 4];
                    af[p][0]=(_Float16)v0.x; af[p][1]=(_Float16)v0.y;
                    af[p][2]=(_Float16)v0.z; af[p][3]=(_Float16)v0.w;
                    af[p][4]=(_Float16)v1.x; af[p][5]=(_Float16)v1.y;
                    af[p][6]=(_Float16)v1.z; af[p][7]=(_Float16)v1.w;
                }
                #pragma unroll
                for (int nf = 0; nf < 4; ++nf) {
                    f16x8 bf = *(const f16x8*)&Wl[((nf * 32 + kiG) * 64 + l) * 8];
                    acc[0][nf] = __builtin_amdgcn_mfma_f32_16x16x32_f16(af[0], bf, acc[0][nf], 0, 0, 0);
                    acc[1][nf] = __builtin_amdgcn_mfma_f32_16x16x32_f16(af[1], bf, acc[1][nf], 0, 0, 0);
                }
            }
            #pragma unroll
            for (int p = 0; p < 2; ++p)
                #pragma unroll
                for (int nf = 0; nf < 4; ++nf)
                    #pragma unroll
                    for (int i = 0; i < 4; ++i) {
                        _Float16 hf = (_Float16)(acc[p][nf][i] + bb0[nf]);
                        unsigned short us; __builtin_memcpy(&us, &hf, 2);
                        unsigned up = us;
                        unsigned op = (unsigned)__shfl_xor((int)up, 1);
                        if (!(l & 1)) {
                            const int m = (w * 2 + p) * 16 + (l >> 4) * 4 + i;
                            size_t off = (((size_t)(c & 3) * 8 + (m >> 5)) * B_ + (m & 31)) * G4_
                                       + gbase + nf * 16 + ((l & 15) & ~1);
                            stA32((unsigned*)&xzr[off], up | (op << 16));
                        }
                    }
            asm volatile("s_waitcnt vmcnt(0)" ::: "memory");
            __syncthreads();
            if (tid == 0) stA32(&ctr[384 + e], (unsigned)(c + 1));
        }
        return;
    }

    // ============================ RECURRENCE DOMAINS (64+64 blocks x 16 cols) ============================
    const int dom = (bid >= 64);
    const int db  = bid & 63;
    const int jb  = db * 16;

    _Float16* stA = (_Float16*)smem;
    float*    red = (float*)(smem + (dom ? 132096 : 66048));
    #define RED(slot, row, col) red[((slot) * 16 + (row)) * 17 + (col)]

    f16x8 wf[32];
    const int gq = w & 3;
    const int myrow = gq * 16 + (l & 15);
    if (dom == 0) {
        load_wfrags(U0, jb, myrow, koff, true, wf, stA);
    } else {
        const int rl0 = w >> 2;
        load_wfrags(W1, jb, myrow, koff, (rl0 == 0), wf, stA);
        load_wfrags(U1, jb, myrow, koff, (rl0 == 1), wf, stA);
    }

    const int cidx = w * 64 + l;
    const int cb = cidx >> 2, j4 = (cidx & 3) * 4;
    float creg[4] = {0.f, 0.f, 0.f, 0.f};
    float bias_[4][4];
    if (dom == 1 && w < 2) {
        #pragma unroll
        for (int g = 0; g < 4; ++g)
            #pragma unroll
            for (int c = 0; c < 4; ++c)
                bias_[g][c] = b1[(size_t)g * H_ + jb + j4 + c];
    }
    const int mt = w >> 2;
    const int rl = w >> 2;

    if (dom == 0) {
        // -------------------- layer 0 --------------------
        for (int t = 0; t < T_; ++t) {
            // xz chunk availability: once per 8 steps (engine runs ~4 ahead)
            if (w < 2 && (t & 7) == 0) {
                const unsigned xt = (unsigned)((t >> 3) + 1);
                while (!__all((int)(ldA(&ctr[384 + l]) >= xt))) __builtin_amdgcn_s_sleep(1);
                asm volatile("" ::: "memory");
            }
            // stage h1(t-1): data-as-flag poll (all 8 waves)
            const char* src = t ? (const char*)(h1 + (size_t)(t - 1) * B_ * H_) : (const char*)zp;
            stage_poll(src, smem, tid);
            // combine waves: issue xz bypass loads (consumed after S3)
            unsigned long long xzq[4];
            if (w < 2) {
                const size_t xbase = (((size_t)((t >> 3) & 3) * 8 + (t & 7)) * B_ + cb) * G4_ + jb + j4;
                #pragma unroll
                for (int gg = 0; gg < 4; ++gg) xzq[gg] = ldA64(&xzr[xbase + gg * 1024]);
            }
            __syncthreads();   // S2: stage visible

            const _Float16* ar = stA + (mt * 16 + (l & 15)) * ROWP;
            f32x4 ac0 = {0,0,0,0}, ac1 = {0,0,0,0}, ac2 = {0,0,0,0}, ac3 = {0,0,0,0};
            #pragma unroll
            for (int k = 0; k < 32; k += 4) {
                ac0 = __builtin_amdgcn_mfma_f32_16x16x32_f16(*(const f16x8*)&ar[(k+0)*32 + koff], wf[k+0], ac0, 0, 0, 0);
                ac1 = __builtin_amdgcn_mfma_f32_16x16x32_f16(*(const f16x8*)&ar[(k+1)*32 + koff], wf[k+1], ac1, 0, 0, 0);
                ac2 = __builtin_amdgcn_mfma_f32_16x16x32_f16(*(const f16x8*)&ar[(k+2)*32 + koff], wf[k+2], ac2, 0, 0, 0);
                ac3 = __builtin_amdgcn_mfma_f32_16x16x32_f16(*(const f16x8*)&ar[(k+3)*32 + koff], wf[k+3], ac3, 0, 0, 0);
            }
            f32x4 acc = (ac0 + ac1) + (ac2 + ac3);
            #pragma unroll
            for (int i = 0; i < 4; ++i)
                RED(mt * 4 + gq, (l >> 4) * 4 + i, (l & 15)) = acc[i];
            __syncthreads();   // S3: red ready, stA free

            if (w < 2) {
                asm volatile("s_waitcnt vmcnt(0)" ::: "memory");   // xz loads landed
                const int rmt = cb >> 4, row = cb & 15;
                unsigned long long pk = 0;
                #pragma unroll
                for (int c = 0; c < 4; ++c) {
                    float z[4];
                    #pragma unroll
                    for (int gg = 0; gg < 4; ++gg) {
                        float xv = f16bits_to_f((unsigned short)((xzq[gg] >> (16 * c)) & 0xffffu));
                        z[gg] = RED(rmt * 4 + gg, row, j4 + c) + xv;
                    }
                    float ig = hardsig(z[0]), fg = hardsig(z[1]);
                    float gv = fast_tanh(z[2]), og = hardsig(z[3]);
                    creg[c] = fg * creg[c] + ig * gv;
                    float hv = og * fast_tanh(creg[c]);
                    _Float16 hf = (_Float16)hv;
                    unsigned short us; __builtin_memcpy(&us, &hf, 2);
                    pk |= ((unsigned long long)us) << (16 * c);
                }
                stA64(&h1[((size_t)t * B_ + cb) * H_ + jb + j4], pk);   // fire-and-forget
                if ((t & 7) == 7) {   // coarse ring-guard flag (per wave, ACKed)
                    asm volatile("s_waitcnt vmcnt(0)" ::: "memory");
                    if (l == 0) stA32(&ctr[db * 2 + w], (unsigned)(t + 1));
                }
            }
        }
    } else {
        // -------------------- layer 1 (no flags at all) --------------------
        _Float16* stB = (_Float16*)(smem + 66048);
        for (int t = 0; t < T_; ++t) {
            const char* s2 = t ? (const char*)(h2 + (size_t)(t - 1) * B_ * H_) : (const char*)zp;
            stage_poll(s2, (char*)stB, tid);    // usually already visible
            const char* s1 = (const char*)(h1 + (size_t)t * B_ * H_);
            stage_poll(s1, smem, tid);          // the fresh dependency
            __syncthreads();   // S2

            const _Float16* ab = (rl ? stB : stA);
            const _Float16* ar0 = ab + (l & 15) * ROWP;
            const _Float16* ar1 = ab + (16 + (l & 15)) * ROWP;
            f32x4 ac0 = {0,0,0,0}, ac1 = {0,0,0,0};
            #pragma unroll
            for (int k = 0; k < 32; ++k) {
                const int kk = k * 32 + koff;
                f16x8 bfr = wf[k];
                ac0 = __builtin_amdgcn_mfma_f32_16x16x32_f16(*(const f16x8*)&ar0[kk], bfr, ac0, 0, 0, 0);
                ac1 = __builtin_amdgcn_mfma_f32_16x16x32_f16(*(const f16x8*)&ar1[kk], bfr, ac1, 0, 0, 0);
            }
            #pragma unroll
            for (int i = 0; i < 4; ++i) {
                RED(rl * 8 + 0 * 4 + gq, (l >> 4) * 4 + i, (l & 15)) = ac0[i];
                RED(rl * 8 + 1 * 4 + gq, (l >> 4) * 4 + i, (l & 15)) = ac1[i];
            }
            __syncthreads();   // S3

            if (w < 2) {
                const int rmt = cb >> 4, row = cb & 15;
                unsigned long long pk = 0;
                float hv4[4];
                #pragma unroll
                for (int c = 0; c < 4; ++c) {
                    float z[4];
                    #pragma unroll
                    for (int gg = 0; gg < 4; ++gg)
                        z[gg] = RED(0 + rmt * 4 + gg, row, j4 + c)
                              + RED(8 + rmt * 4 + gg, row, j4 + c) + bias_[gg][c];
                    float ig = hardsig(z[0]), fg = hardsig(z[1]);
                    float gv = fast_tanh(z[2]), og = hardsig(z[3]);
                    creg[c] = fg * creg[c] + ig * gv;
                    hv4[c] = og * fast_tanh(creg[c]);
                    _Float16 hf = (_Float16)hv4[c];
                    unsigned short us; __builtin_memcpy(&us, &hf, 2);
                    pk |= ((unsigned long long)us) << (16 * c);
                }
                stA64(&h2[((size_t)t * B_ + cb) * H_ + jb + j4], pk);   // fire-and-forget
                if (t == T_ - 1)
                    *(float4*)&out[(size_t)cb * H_ + jb + j4] = make_float4(hv4[0], hv4[1], hv4[2], hv4[3]);
            }
        }
    }
}

extern "C" void kernel_launch(void* const* d_in, const int* in_sizes, int n_in,
                              void* d_out, int out_size, void* d_ws, size_t ws_size,
                              hipStream_t stream) {
    const float* x  = (const float*)d_in[0];
    const float* W0 = (const float*)d_in[1];
    const float* U0 = (const float*)d_in[2];
    const float* b0 = (const float*)d_in[3];
    const float* W1 = (const float*)d_in[4];
    const float* U1 = (const float*)d_in[5];
    const float* b1 = (const float*)d_in[6];
    float* out = (float*)d_out;

    char* ws = (char*)d_ws;
    const size_t off_h1 = 0;          // 32 MiB  h1 fp16 [T][B][H]  (0xFF sentinel)
    const size_t off_h2 = 33554432;   // 32 MiB  h2 fp16 [T][B][H]  (0xFF sentinel)
    const size_t off_xz = 67108864;   //  8 MiB  xz ring fp16
    const size_t off_zp = 75497472;   // 64 KiB  fp16 zeros
    const size_t off_ct = 75563008;   //  8 KiB  flags

    _Float16* h1  = (_Float16*)(ws + off_h1);
    _Float16* h2  = (_Float16*)(ws + off_h2);
    _Float16* xzr = (_Float16*)(ws + off_xz);
    _Float16* zp  = (_Float16*)(ws + off_zp);
    unsigned* ctr = (unsigned*)(ws + off_ct);

    // sentinel-fill h1/h2; zero zp + flags (graph-capture safe, every launch)
    hipMemsetAsync(ws, 0xFF, 67108864, stream);
    hipMemsetAsync(ws + off_zp, 0, 65536 + 8192, stream);

    hipLaunchKernelGGL(lstm13, dim3(192), dim3(NT), 0, stream,
                       x, W0, U0, b0, W1, U1, b1,
                       h1, h2, xzr, zp, ctr, out);
}